// Round 16
// baseline (91.889 us; speedup 1.0000x reference)
//
#include <hip/hip_runtime.h>

#define DD   64
#define WSH  6            // 64 nodes per window
#define WSZ  64
#define TILE 8192
#define ALGN 32           // reservation granularity (64B line of u16)
#define GMAX 1024
#define SMAX 1024         // self-loop list capacity (expected ~32)
#define CAP  8192         // per-window entry capacity (aligned reservations)
#define RK   512          // relation count (K dim of histogram GEMM)

typedef unsigned int u32;
typedef unsigned short u16;
typedef __attribute__((ext_vector_type(4))) float f32x4;
typedef __attribute__((ext_vector_type(4))) u32 u32x4;
typedef __attribute__((ext_vector_type(8))) short short8;

// es entry u16: local_node(6b) | etype<<6 (9b); 0xFFFF = pad sentinel
// selflist entry u32: node<<9 | etype
// LDS hist: u4[64][512]; word = r*64 + ((t>>3) ^ ((r&7)<<2)), nibble = t&7

__device__ inline u32 f2bf(float x) {
    u32 u = __float_as_uint(x);
    return (u + 0x7FFFu + ((u >> 16) & 1u)) >> 16;
}
__device__ inline float bf2f(u32 b) { return __uint_as_float(b << 16); }
// swizzled u16 index into a [64][64] bf16 LDS tile (16B-chunk XOR)
__device__ inline int swz16(int row, int col) {
    return row * 64 + ((((col >> 3) ^ (row & 7)) << 3) | (col & 7));
}
// pack hi16 of two f32 (exact bf16 for small ints) -> u32
__device__ inline u32 pack_bf_hi(float lo, float hi) {
    return __builtin_amdgcn_perm(__float_as_uint(hi), __float_as_uint(lo),
                                 0x07060302u);
}

// ---------------------------------------------------------------------------
// blocks 0..7: relT slice + partial ctx colsum (atomic); block 8: w1t/w2t.
__global__ __launch_bounds__(512)
void k_prep(const float* __restrict__ rel, int R, float* __restrict__ ctxsum,
            u16* __restrict__ relT, const float* __restrict__ w1,
            const float* __restrict__ w2, u16* __restrict__ w1t,
            u16* __restrict__ w2t) {
    if (blockIdx.x == 8) {
        for (int i = threadIdx.x; i < DD * DD; i += 512) {
            int j = i >> 6, k = i & 63;
            w1t[i] = (u16)f2bf(w1[j * 2 * DD + k] + w1[j * 2 * DD + DD + k]);
            w2t[i] = (u16)f2bf(w2[i]);
        }
        return;
    }
    __shared__ float part[8][DD];
    int k0 = blockIdx.x * (RK / 8);     // 64 rows per block
    int d  = threadIdx.x & 63;
    int rg = threadIdx.x >> 6;          // 0..7
    float s = 0.f;
    #pragma unroll
    for (int i = 0; i < 8; ++i) {
        int k = k0 + rg * 8 + i;
        float v = rel[k * DD + d];
        relT[d * RK + k] = (u16)f2bf(v);
        s += v;
    }
    part[rg][d] = s;
    __syncthreads();
    if (threadIdx.x < DD) {
        float t = 0.f;
        #pragma unroll
        for (int i = 0; i < 8; ++i) t += part[i][threadIdx.x];
        atomicAdd(&ctxsum[threadIdx.x], t);
    }
}

// ---------------------------------------------------------------------------
// Placement with 64B-line-aligned reservations; no register staging (pass 2
// re-reads src/dst/etype from L2). Each 64B es line owned by one block.
__global__ __launch_bounds__(512)
void k_gplace(const int* __restrict__ src, const int* __restrict__ dst,
              const int* __restrict__ etype, int* __restrict__ gcur,
              u16* __restrict__ es, u32* __restrict__ selflist,
              int* __restrict__ slcnt, int E, int G) {
    __shared__ int lcnt[GMAX];
    __shared__ int lbase[GMAX];
    for (int i = threadIdx.x; i < G; i += 512) lcnt[i] = 0;
    __syncthreads();
    int t0 = blockIdx.x * TILE;
    int t1 = min(t0 + TILE, E);
    for (int i = t0 + threadIdx.x; i < t1; i += 512) {
        int s = src[i], d = dst[i];
        atomicAdd(&lcnt[s >> WSH], 1);
        if (s != d) atomicAdd(&lcnt[d >> WSH], 1);
    }
    __syncthreads();
    for (int g = threadIdx.x; g < G; g += 512) {
        int c = lcnt[g];
        lbase[g] = c ? atomicAdd(&gcur[g], (c + ALGN - 1) & ~(ALGN - 1)) : 0;
        lcnt[g] = 0;
    }
    __syncthreads();
    for (int i = t0 + threadIdx.x; i < t1; i += 512) {
        int s = src[i], d = dst[i];
        u32 t = (u32)etype[i];
        int gs = s >> WSH;
        int p = lbase[gs] + atomicAdd(&lcnt[gs], 1);
        if (p < CAP) es[(size_t)gs * CAP + p] = (u16)((u32)(s & 63) | (t << 6));
        if (s != d) {
            int gd = d >> WSH;
            int q = lbase[gd] + atomicAdd(&lcnt[gd], 1);
            if (q < CAP) es[(size_t)gd * CAP + q] = (u16)((u32)(d & 63) | (t << 6));
        } else {
            int p2 = atomicAdd(slcnt, 1);
            if (p2 < SMAX) selflist[p2] = ((u32)s << 9) | t;
        }
    }
    __syncthreads();
    for (int g = threadIdx.x; g < G; g += 512) {
        int c = lcnt[g];
        if (c) {
            int pad = (c + ALGN - 1) & ~(ALGN - 1);
            int base = lbase[g];
            for (int p = c; p < pad; ++p) {
                int q = base + p;
                if (q < CAP) es[(size_t)g * CAP + q] = 0xFFFFu;
            }
        }
    }
}

// ---------------------------------------------------------------------------
// PERSISTENT fused window kernel: 391 blocks x 2 windows each. Weights staged
// once; per window: hist -> deg -> 3-GEMM MFMA chain -> blended store.
__global__ __launch_bounds__(512, 2)
void k_win(const u16* __restrict__ es, const int* __restrict__ gcur,
           const u16* __restrict__ relT, const u16* __restrict__ w1t,
           const u16* __restrict__ w2t, const float* __restrict__ ctxsum,
           int R, const float* __restrict__ b1, const float* __restrict__ b2,
           const float* __restrict__ strength, float* __restrict__ out,
           const u32* __restrict__ selflist, const int* __restrict__ slcnt,
           const float* __restrict__ w1a, const float* __restrict__ b1a,
           const float* __restrict__ w2a, const float* __restrict__ b2a,
           int N, int GW) {
    __shared__ __align__(16) u32 Hn[WSZ * RK / 8];   // 16 KB; H1b aliases
    __shared__ __align__(16) u16 rt[2][WSZ * DD];    // 16 KB relT chunk dbuf
    __shared__ __align__(16) u16 w1s[DD * DD];       // 8 KB (swizzled)
    __shared__ __align__(16) u16 w2s[DD * DD];       // 8 KB (swizzled)
    __shared__ __align__(16) u16 Fb[WSZ * DD];       // 8 KB (swizzled)
    __shared__ int cnts[WSZ];
    __shared__ int selfc[WSZ];
    __shared__ float invd[WSZ];
    __shared__ float b1s[DD], b2s[DD], ctx_s[DD];
    u16* H1b = (u16*)Hn;                             // overlay (8 KB of 16)

    int tid = threadIdx.x;
    int lane = tid & 63;
    int wv = tid >> 6;                  // 8 waves
    int scol = tid >> 3, skk = (tid & 7) * 8;        // staging col, k-offset

    if (tid < DD) {
        b1s[tid] = b1[tid]; b2s[tid] = b2[tid];
        ctx_s[tid] = ctxsum[tid] / (float)R;
    }
    {   // stage weights once (coalesced 16B/thread; swizzled LDS)
        short8 wv1 = *(const short8*)(w1t + scol * DD + skk);
        short8 wv2 = *(const short8*)(w2t + scol * DD + skk);
        *(short8*)(w1s + swz16(scol, skk)) = wv1;
        *(short8*)(w2s + swz16(scol, skk)) = wv2;
    }
    float sc = fminf(fmaxf(strength[0], 0.f), 0.3f);
    int scount = min(*slcnt, SMAX);

    int mb = wv >> 1;                   // 0..3 row-block
    int nb0 = (wv & 1) * 2;             // col-blocks nb0, nb0+1
    int arow = mb * 16 + (lane & 15);
    int kgrp = (lane >> 4) * 8;         // 0,8,16,24
    int col0 = nb0 * 16 + (lane & 15);
    int col1 = col0 + 16;

    for (int w = blockIdx.x; w < GW; w += gridDim.x) {
        __syncthreads();                // prev iter's LDS reads complete
        for (int i = tid; i < WSZ * RK / 8; i += 512) Hn[i] = 0;
        if (tid < WSZ) selfc[tid] = 0;
        int cntE = min(gcur[w], CAP);
        short8 stg0 = *(const short8*)(relT + scol * RK + skk);
        __syncthreads();                // Hn zeroed

        // --- histogram build: 16B vector loads ---
        const u32x4* es128 = (const u32x4*)(es + (size_t)w * CAP);
        int nv = cntE >> 3;             // u32x4 count (8 entries each)
        for (int i = tid; i < nv; i += 512) {
            u32x4 v4 = es128[i];
            #pragma unroll
            for (int c = 0; c < 4; ++c) {
                u32 v2 = v4[c];
                #pragma unroll
                for (int h = 0; h < 2; ++h) {
                    u32 v = h ? (v2 >> 16) : (v2 & 0xFFFFu);
                    if (v == 0xFFFFu) continue;
                    int r = (int)(v & 63);
                    int t = (int)((v >> 6) & 0x1FF);
                    int word = r * 64 + ((t >> 3) ^ ((r & 7) << 2));
                    atomicAdd(&Hn[word], 1u << ((t & 7) * 4));
                }
            }
        }
        for (int i = tid; i < scount; i += 512) {
            int n = (int)(selflist[i] >> 9);
            if ((n >> WSH) == w) atomicAdd(&selfc[n & 63], 1);
        }
        __syncthreads();
        {   // deg rowsum: 8 threads/row; shfl-reduce within 8 lanes
            int row = tid >> 3;
            int s = 0;
            int w0 = row * 64 + (tid & 7) * 8;
            #pragma unroll
            for (int i = 0; i < 8; ++i) {
                u32 v = Hn[w0 + i];
                u32 a = (v & 0x0F0F0F0Fu) + ((v >> 4) & 0x0F0F0F0Fu);
                s += (int)((a & 0xFF) + ((a >> 8) & 0xFF) +
                           ((a >> 16) & 0xFF) + (a >> 24));
            }
            s += __shfl_down(s, 4); s += __shfl_down(s, 2); s += __shfl_down(s, 1);
            if ((tid & 7) == 0) cnts[row] = s;
        }
        *(short8*)(rt[0] + swz16(scol, skk)) = stg0;    // relT chunk 0
        __syncthreads();
        if (tid < WSZ) {
            int c = cnts[tid];
            invd[tid] = c ? 1.f / (float)c : 0.f;
        }
        // preload the wave's entire A row (16 words = 64B) into registers
        u32 aw[16];
        {
            int abase = arow * 64;
            int kg = kgrp >> 3;         // 0..3
            #pragma unroll
            for (int ks = 0; ks < 16; ++ks)
                aw[ks] = Hn[abase + ((ks * 4 + kg) ^ ((arow & 7) << 2))];
        }
        __syncthreads();

        // ---- MFMA1: F = H @ rel (B from LDS dbuf), scaled by invd ----
        f32x4 acc0 = {0.f, 0.f, 0.f, 0.f}, acc1 = {0.f, 0.f, 0.f, 0.f};
        #pragma unroll
        for (int q = 0; q < 8; ++q) {   // 8 chunks of K=64
            short8 nxt;
            if (q < 7)
                nxt = *(const short8*)(relT + scol * RK + (q + 1) * 64 + skk);
            const u16* rb = rt[q & 1];
            #pragma unroll
            for (int s2 = 0; s2 < 2; ++s2) {
                int koff = s2 * 32 + kgrp;
                u32 v = aw[q * 2 + s2];
                u32 af32[4];
                #pragma unroll
                for (int e = 0; e < 4; ++e) {
                    float g0 = (float)((v >> (8 * e)) & 0xFu);
                    float g1 = (float)((v >> (8 * e + 4)) & 0xFu);
                    af32[e] = pack_bf_hi(g0, g1);
                }
                short8 af = *(short8*)af32;
                const short8* bp0 = (const short8*)
                    (rb + col0 * 64 + (((koff >> 3) ^ (col0 & 7)) << 3));
                const short8* bp1 = (const short8*)
                    (rb + col1 * 64 + (((koff >> 3) ^ (col1 & 7)) << 3));
                acc0 = __builtin_amdgcn_mfma_f32_16x16x32_bf16(af, *bp0, acc0, 0, 0, 0);
                acc1 = __builtin_amdgcn_mfma_f32_16x16x32_bf16(af, *bp1, acc1, 0, 0, 0);
            }
            if (q < 7) {
                __syncthreads();        // all reads of rt[(q+1)&1] done
                *(short8*)(rt[(q + 1) & 1] + swz16(scol, skk)) = nxt;
                __syncthreads();
            }
        }
        __syncthreads();
        #pragma unroll
        for (int r = 0; r < 4; ++r) {
            int row = mb * 16 + (lane >> 4) * 4 + r;
            float iv = invd[row];
            Fb[swz16(row, col0)] = (u16)f2bf(acc0[r] * iv);
            Fb[swz16(row, col1)] = (u16)f2bf(acc1[r] * iv);
        }
        __syncthreads();

        // ---- MFMA2: H1 = relu(F @ w1e^T + b1) -> H1b (overlays Hn) ----
        f32x4 ac20 = {0.f, 0.f, 0.f, 0.f}, ac21 = {0.f, 0.f, 0.f, 0.f};
        #pragma unroll
        for (int ks = 0; ks < 2; ++ks) {
            int kb = ks * 32 + kgrp;
            const short8* ap = (const short8*)
                (Fb + arow * 64 + (((kb >> 3) ^ (arow & 7)) << 3));
            const short8* bp0 = (const short8*)
                (w1s + col0 * 64 + (((kb >> 3) ^ (col0 & 7)) << 3));
            const short8* bp1 = (const short8*)
                (w1s + col1 * 64 + (((kb >> 3) ^ (col1 & 7)) << 3));
            ac20 = __builtin_amdgcn_mfma_f32_16x16x32_bf16(*ap, *bp0, ac20, 0, 0, 0);
            ac21 = __builtin_amdgcn_mfma_f32_16x16x32_bf16(*ap, *bp1, ac21, 0, 0, 0);
        }
        __syncthreads();
        #pragma unroll
        for (int r = 0; r < 4; ++r) {
            int row = mb * 16 + (lane >> 4) * 4 + r;
            H1b[swz16(row, col0)] = (u16)f2bf(fmaxf(ac20[r] + b1s[col0], 0.f));
            H1b[swz16(row, col1)] = (u16)f2bf(fmaxf(ac21[r] + b1s[col1], 0.f));
        }
        __syncthreads();

        // ---- MFMA3: O = H1 @ w2^T + b2; blend & store ----
        f32x4 ac30 = {0.f, 0.f, 0.f, 0.f}, ac31 = {0.f, 0.f, 0.f, 0.f};
        #pragma unroll
        for (int ks = 0; ks < 2; ++ks) {
            int kb = ks * 32 + kgrp;
            const short8* ap = (const short8*)
                (H1b + arow * 64 + (((kb >> 3) ^ (arow & 7)) << 3));
            const short8* bp0 = (const short8*)
                (w2s + col0 * 64 + (((kb >> 3) ^ (col0 & 7)) << 3));
            const short8* bp1 = (const short8*)
                (w2s + col1 * 64 + (((kb >> 3) ^ (col1 & 7)) << 3));
            ac30 = __builtin_amdgcn_mfma_f32_16x16x32_bf16(*ap, *bp0, ac30, 0, 0, 0);
            ac31 = __builtin_amdgcn_mfma_f32_16x16x32_bf16(*ap, *bp1, ac31, 0, 0, 0);
        }
        #pragma unroll
        for (int r = 0; r < 4; ++r) {
            int row = mb * 16 + (lane >> 4) * 4 + r;
            int n = (w << WSH) + row;
            if (n >= N) continue;
            int c = cnts[row];
            if (c > 0 && selfc[row] == c) continue;  // all-self: branch a
            #pragma unroll
            for (int q = 0; q < 2; ++q) {
                int col = (nb0 + q) * 16 + (lane & 15);
                float o = (q == 0 ? ac30[r] : ac31[r]) + b2s[col];
                float f = bf2f(Fb[swz16(row, col)]);
                out[n * DD + col] = (c == 0) ? ctx_s[col] : (1.f - sc) * f + sc * o;
            }
        }
        // rare all-self nodes: branch-a MLP inline (wave 0; ~never executes)
        if (wv == 0) {
            bool fl;
            {
                int c = cnts[lane];
                fl = (c > 0) && (selfc[lane] == c) && ((w << WSH) + lane < N);
            }
            unsigned long long m = __ballot(fl);
            float cx = ctx_s[lane];
            while (m) {
                int rr = __ffsll(m) - 1;
                m &= m - 1;
                int n = (w << WSH) + rr;
                float f = bf2f(Fb[swz16(rr, lane)]);
                float h = b1a[lane];
                for (int k = 0; k < DD; ++k)
                    h = fmaf(__shfl(f, k), w1a[lane * 2 * DD + k], h);
                for (int k = 0; k < DD; ++k)
                    h = fmaf(__shfl(cx, k), w1a[lane * 2 * DD + DD + k], h);
                h = fmaxf(h, 0.f);
                float o = b2a[lane];
                for (int k = 0; k < DD; ++k)
                    o = fmaf(__shfl(h, k), w2a[lane * DD + k], o);
                out[n * DD + lane] = (1.f - sc) * f + sc * o;
            }
        }
    }
}

// ---------------------------------------------------------------------------
extern "C" void kernel_launch(void* const* d_in, const int* in_sizes, int n_in,
                              void* d_out, int out_size, void* d_ws, size_t ws_size,
                              hipStream_t stream) {
    const int*   edge_index = (const int*)d_in[0];     // [2, E]
    const int*   etype      = (const int*)d_in[1];     // [E]
    const float* rel        = (const float*)d_in[2];   // [R, 64]
    const float* w1a        = (const float*)d_in[3];
    const float* b1a        = (const float*)d_in[4];
    const float* w2a        = (const float*)d_in[5];
    const float* b2a        = (const float*)d_in[6];
    const float* w1b        = (const float*)d_in[7];
    const float* b1b        = (const float*)d_in[8];
    const float* w2b        = (const float*)d_in[9];
    const float* b2b        = (const float*)d_in[10];
    const float* strength   = (const float*)d_in[11];

    int E = in_sizes[0] / 2;
    int R = in_sizes[2] / DD;   // == RK
    int N = out_size / DD;
    int GW = (N + WSZ - 1) >> WSH;      // 64-node windows

    float* out = (float*)d_out;
    char*  p   = (char*)d_ws;

    // zeroed region
    int*   gcur   = (int*)p;   p += (size_t)GW * sizeof(int);
    int*   slcnt  = (int*)p;   p += sizeof(int);
    float* ctxsum = (float*)p; p += DD * sizeof(float);
    size_t zbytes = (size_t)(p - (char*)d_ws);
    p = (char*)(((size_t)p + 15) & ~(size_t)15);
    // non-zeroed
    u16*   relT     = (u16*)p; p += (size_t)RK * DD * sizeof(u16);
    u16*   w1t      = (u16*)p; p += (size_t)DD * DD * sizeof(u16);
    u16*   w2t      = (u16*)p; p += (size_t)DD * DD * sizeof(u16);
    u32*   selflist = (u32*)p; p += (size_t)SMAX * sizeof(u32);
    u16*   es       = (u16*)p;  // GW*CAP u16 = 12.8 MB (16B-aligned)

    hipMemsetAsync(gcur, 0, zbytes, stream);

    k_prep<<<9, 512, 0, stream>>>(rel, R, ctxsum, relT, w1b, w2b, w1t, w2t);

    const int* src = edge_index;
    const int* dst = edge_index + E;
    int nb = (E + TILE - 1) / TILE;

    k_gplace<<<nb, 512, 0, stream>>>(src, dst, etype, gcur, es,
                                     selflist, slcnt, E, GW);

    int nwb = (GW + 1) / 2;             // persistent: 2 windows per block
    k_win<<<nwb, 512, 0, stream>>>(es, gcur, relT, w1t, w2t, ctxsum, R,
                                   b1b, b2b, strength, out,
                                   selflist, slcnt, w1a, b1a, w2a, b2a, N, GW);
}

// Round 17
// 63.630 us; speedup vs baseline: 1.4441x; 1.4441x over previous
//
#include <hip/hip_runtime.h>

#define DD   64
#define WSH  6            // 64 nodes per window
#define WSZ  64
#define TILE 4096
#define ALGN 16           // reservation granularity (32B sector of u16)
#define GMAX 1024
#define SMAX 1024         // self-loop list capacity (expected ~32)
#define CAP  8192         // per-window entry capacity (aligned reservations)
#define LSTG 20480        // LDS stage entries: 2*TILE + GMAX*(ALGN-1) bound
#define RK   512          // relation count (K dim of histogram GEMM)

typedef unsigned int u32;
typedef unsigned short u16;
typedef __attribute__((ext_vector_type(4))) float f32x4;
typedef __attribute__((ext_vector_type(4))) u32 u32x4;
typedef __attribute__((ext_vector_type(8))) short short8;

// es entry u16: local_node(6b) | etype<<6 (9b); 0xFFFF = pad sentinel
// selflist entry u32: node<<9 | etype
// LDS hist: u4[64][512]; word = r*64 + ((t>>3) ^ ((r&7)<<2)), nibble = t&7

__device__ inline u32 f2bf(float x) {
    u32 u = __float_as_uint(x);
    return (u + 0x7FFFu + ((u >> 16) & 1u)) >> 16;
}
__device__ inline float bf2f(u32 b) { return __uint_as_float(b << 16); }
// swizzled u16 index into a [64][64] bf16 LDS tile (16B-chunk XOR)
__device__ inline int swz16(int row, int col) {
    return row * 64 + ((((col >> 3) ^ (row & 7)) << 3) | (col & 7));
}
// pack hi16 of two f32 (exact bf16 for small ints) -> u32
__device__ inline u32 pack_bf_hi(float lo, float hi) {
    return __builtin_amdgcn_perm(__float_as_uint(hi), __float_as_uint(lo),
                                 0x07060302u);
}

// ---------------------------------------------------------------------------
// blocks 0..7: relT slice + per-block ctx partial (no atomics);
// block 8: w1t/w2t staging + zero gcur[0..G] (covers slcnt at gcur+G).
__global__ __launch_bounds__(512)
void k_prep(const float* __restrict__ rel, int R, float* __restrict__ ctxpart,
            u16* __restrict__ relT, const float* __restrict__ w1,
            const float* __restrict__ w2, u16* __restrict__ w1t,
            u16* __restrict__ w2t, int* __restrict__ gcur, int G) {
    if (blockIdx.x == 8) {
        for (int i = threadIdx.x; i < DD * DD; i += 512) {
            int j = i >> 6, k = i & 63;
            w1t[i] = (u16)f2bf(w1[j * 2 * DD + k] + w1[j * 2 * DD + DD + k]);
            w2t[i] = (u16)f2bf(w2[i]);
        }
        for (int i = threadIdx.x; i < G + 1; i += 512) gcur[i] = 0;
        return;
    }
    __shared__ float part[8][DD];
    int k0 = blockIdx.x * (RK / 8);     // 64 rows per block
    int d  = threadIdx.x & 63;
    int rg = threadIdx.x >> 6;          // 0..7
    float s = 0.f;
    #pragma unroll
    for (int i = 0; i < 8; ++i) {
        int k = k0 + rg * 8 + i;
        float v = rel[k * DD + d];
        relT[d * RK + k] = (u16)f2bf(v);
        s += v;
    }
    part[rg][d] = s;
    __syncthreads();
    if (threadIdx.x < DD) {
        float t = 0.f;
        #pragma unroll
        for (int i = 0; i < 8; ++i) t += part[i][threadIdx.x];
        ctxpart[blockIdx.x * DD + threadIdx.x] = t;
    }
}

// ---------------------------------------------------------------------------
// Placement: count -> padded scan -> LDS group-sorted stage -> wide copy-out.
// All global es stores are 16B vector stores into 32B-aligned single-owner
// sectors (pad = 0xFFFF sentinels), killing the scattered-store transactions.
__global__ __launch_bounds__(512)
void k_gplace(const int* __restrict__ src, const int* __restrict__ dst,
              const int* __restrict__ etype, int* __restrict__ gcur,
              u16* __restrict__ es, u32* __restrict__ selflist,
              int* __restrict__ slcnt, int E, int G) {
    __shared__ int lcnt[GMAX];
    __shared__ int lbase[GMAX];
    __shared__ int loff[GMAX];
    __shared__ int lcur[GMAX];
    __shared__ __align__(32) u16 stage[LSTG];
    int tid = threadIdx.x;
    for (int i = tid; i < GMAX; i += 512) lcnt[i] = 0;
    __syncthreads();
    int t0 = blockIdx.x * TILE;
    int t1 = min(t0 + TILE, E);
    // pass A: count endpoints per window
    for (int i = t0 + tid; i < t1; i += 512) {
        int s = src[i], d = dst[i];
        atomicAdd(&lcnt[s >> WSH], 1);
        if (s != d) atomicAdd(&lcnt[d >> WSH], 1);
    }
    __syncthreads();
    // inclusive scan of PADDED counts (Hillis-Steele, 1024 wide, 512 thr x 2)
    for (int i = tid; i < GMAX; i += 512)
        loff[i] = (i < G) ? ((lcnt[i] + ALGN - 1) & ~(ALGN - 1)) : 0;
    __syncthreads();
    for (int d2 = 1; d2 < GMAX; d2 <<= 1) {
        int v0 = (tid >= d2) ? loff[tid - d2] : 0;
        int v1 = loff[tid + 512 - d2];
        __syncthreads();
        loff[tid] += v0;
        loff[tid + 512] += v1;
        __syncthreads();
    }
    // exclusive start offsets + global reservations
    for (int g = tid; g < G; g += 512) {
        int c = lcnt[g];
        int pad = (c + ALGN - 1) & ~(ALGN - 1);
        int st = loff[g] - pad;
        loff[g] = st;
        lcur[g] = st;
        lbase[g] = c ? atomicAdd(&gcur[g], pad) : 0;
    }
    __syncthreads();
    // pass B: place into LDS stage (group-sorted)
    for (int i = t0 + tid; i < t1; i += 512) {
        int s = src[i], d = dst[i];
        u32 t = (u32)etype[i];
        int gs = s >> WSH;
        int p = atomicAdd(&lcur[gs], 1);
        stage[p] = (u16)((u32)(s & 63) | (t << 6));
        if (s != d) {
            int gd = d >> WSH;
            int q = atomicAdd(&lcur[gd], 1);
            stage[q] = (u16)((u32)(d & 63) | (t << 6));
        } else {
            int p2 = atomicAdd(slcnt, 1);
            if (p2 < SMAX) selflist[p2] = ((u32)s << 9) | t;
        }
    }
    __syncthreads();
    // sentinel-fill pad tails
    for (int g = tid; g < G; g += 512) {
        int c = lcnt[g];
        if (!c) continue;
        int pad = (c + ALGN - 1) & ~(ALGN - 1);
        int st = loff[g];
        for (int p = st + c; p < st + pad; ++p) stage[p] = 0xFFFFu;
    }
    __syncthreads();
    // wide copy-out: 2x16B per 32-entry... per 16-entry chunk (32B sectors)
    for (int g = tid; g < G; g += 512) {
        int c = lcnt[g];
        if (!c) continue;
        int pad = (c + ALGN - 1) & ~(ALGN - 1);
        int st = loff[g];
        int gb = lbase[g];
        u16* dp = es + (size_t)g * CAP + gb;
        for (int off = 0; off < pad; off += 16) {
            if (gb + off + 16 <= CAP) {
                u32x4 a = *(const u32x4*)(stage + st + off);
                u32x4 b = *(const u32x4*)(stage + st + off + 8);
                *(u32x4*)(dp + off) = a;
                *(u32x4*)(dp + off + 8) = b;
            }
        }
    }
}

// ---------------------------------------------------------------------------
// PERSISTENT fused window kernel: ~2 windows per block. Weights staged once;
// per window: hist -> deg -> 3-GEMM MFMA chain -> blended store.
__global__ __launch_bounds__(512, 2)
void k_win(const u16* __restrict__ es, const int* __restrict__ gcur,
           const u16* __restrict__ relT, const u16* __restrict__ w1t,
           const u16* __restrict__ w2t, const float* __restrict__ ctxpart,
           int R, const float* __restrict__ b1, const float* __restrict__ b2,
           const float* __restrict__ strength, float* __restrict__ out,
           const u32* __restrict__ selflist, const int* __restrict__ slcnt,
           const float* __restrict__ w1a, const float* __restrict__ b1a,
           const float* __restrict__ w2a, const float* __restrict__ b2a,
           int N, int GW) {
    __shared__ __align__(16) u32 Hn[WSZ * RK / 8];   // 16 KB; H1b aliases
    __shared__ __align__(16) u16 rt[2][WSZ * DD];    // 16 KB relT chunk dbuf
    __shared__ __align__(16) u16 w1s[DD * DD];       // 8 KB (swizzled)
    __shared__ __align__(16) u16 w2s[DD * DD];       // 8 KB (swizzled)
    __shared__ __align__(16) u16 Fb[WSZ * DD];       // 8 KB (swizzled)
    __shared__ int cnts[WSZ];
    __shared__ int selfc[WSZ];
    __shared__ float invd[WSZ];
    __shared__ float b1s[DD], b2s[DD], ctx_s[DD];
    u16* H1b = (u16*)Hn;                             // overlay (8 KB of 16)

    int tid = threadIdx.x;
    int lane = tid & 63;
    int wv = tid >> 6;                  // 8 waves
    int scol = tid >> 3, skk = (tid & 7) * 8;        // staging col, k-offset

    if (tid < DD) {
        b1s[tid] = b1[tid]; b2s[tid] = b2[tid];
        float t = 0.f;
        #pragma unroll
        for (int i = 0; i < 8; ++i) t += ctxpart[i * DD + tid];
        ctx_s[tid] = t / (float)R;
    }
    {   // stage weights once (coalesced 16B/thread; swizzled LDS)
        short8 wv1 = *(const short8*)(w1t + scol * DD + skk);
        short8 wv2 = *(const short8*)(w2t + scol * DD + skk);
        *(short8*)(w1s + swz16(scol, skk)) = wv1;
        *(short8*)(w2s + swz16(scol, skk)) = wv2;
    }
    float sc = fminf(fmaxf(strength[0], 0.f), 0.3f);
    int scount = min(*slcnt, SMAX);

    int mb = wv >> 1;                   // 0..3 row-block
    int nb0 = (wv & 1) * 2;             // col-blocks nb0, nb0+1
    int arow = mb * 16 + (lane & 15);
    int kgrp = (lane >> 4) * 8;         // 0,8,16,24
    int col0 = nb0 * 16 + (lane & 15);
    int col1 = col0 + 16;

    for (int w = blockIdx.x; w < GW; w += gridDim.x) {
        __syncthreads();                // prev iter's LDS reads complete
        for (int i = tid; i < WSZ * RK / 8; i += 512) Hn[i] = 0;
        if (tid < WSZ) selfc[tid] = 0;
        int cntE = min(gcur[w], CAP);
        short8 stg0 = *(const short8*)(relT + scol * RK + skk);
        __syncthreads();                // Hn zeroed

        // --- histogram build: 16B vector loads ---
        const u32x4* es128 = (const u32x4*)(es + (size_t)w * CAP);
        int nv = cntE >> 3;             // u32x4 count (8 entries each)
        for (int i = tid; i < nv; i += 512) {
            u32x4 v4 = es128[i];
            #pragma unroll
            for (int c = 0; c < 4; ++c) {
                u32 v2 = v4[c];
                #pragma unroll
                for (int h = 0; h < 2; ++h) {
                    u32 v = h ? (v2 >> 16) : (v2 & 0xFFFFu);
                    if (v == 0xFFFFu) continue;
                    int r = (int)(v & 63);
                    int t = (int)((v >> 6) & 0x1FF);
                    int word = r * 64 + ((t >> 3) ^ ((r & 7) << 2));
                    atomicAdd(&Hn[word], 1u << ((t & 7) * 4));
                }
            }
        }
        for (int i = tid; i < scount; i += 512) {
            int n = (int)(selflist[i] >> 9);
            if ((n >> WSH) == w) atomicAdd(&selfc[n & 63], 1);
        }
        __syncthreads();
        {   // deg rowsum: 8 threads/row; shfl-reduce within 8 lanes
            int row = tid >> 3;
            int s = 0;
            int w0 = row * 64 + (tid & 7) * 8;
            #pragma unroll
            for (int i = 0; i < 8; ++i) {
                u32 v = Hn[w0 + i];
                u32 a = (v & 0x0F0F0F0Fu) + ((v >> 4) & 0x0F0F0F0Fu);
                s += (int)((a & 0xFF) + ((a >> 8) & 0xFF) +
                           ((a >> 16) & 0xFF) + (a >> 24));
            }
            s += __shfl_down(s, 4); s += __shfl_down(s, 2); s += __shfl_down(s, 1);
            if ((tid & 7) == 0) cnts[row] = s;
        }
        *(short8*)(rt[0] + swz16(scol, skk)) = stg0;    // relT chunk 0
        __syncthreads();
        if (tid < WSZ) {
            int c = cnts[tid];
            invd[tid] = c ? 1.f / (float)c : 0.f;
        }
        // preload the wave's entire A row (16 words = 64B) into registers
        u32 aw[16];
        {
            int abase = arow * 64;
            int kg = kgrp >> 3;         // 0..3
            #pragma unroll
            for (int ks = 0; ks < 16; ++ks)
                aw[ks] = Hn[abase + ((ks * 4 + kg) ^ ((arow & 7) << 2))];
        }
        __syncthreads();

        // ---- MFMA1: F = H @ rel (B from LDS dbuf), scaled by invd ----
        f32x4 acc0 = {0.f, 0.f, 0.f, 0.f}, acc1 = {0.f, 0.f, 0.f, 0.f};
        #pragma unroll
        for (int q = 0; q < 8; ++q) {   // 8 chunks of K=64
            short8 nxt;
            if (q < 7)
                nxt = *(const short8*)(relT + scol * RK + (q + 1) * 64 + skk);
            const u16* rb = rt[q & 1];
            #pragma unroll
            for (int s2 = 0; s2 < 2; ++s2) {
                int koff = s2 * 32 + kgrp;
                u32 v = aw[q * 2 + s2];
                u32 af32[4];
                #pragma unroll
                for (int e = 0; e < 4; ++e) {
                    float g0 = (float)((v >> (8 * e)) & 0xFu);
                    float g1 = (float)((v >> (8 * e + 4)) & 0xFu);
                    af32[e] = pack_bf_hi(g0, g1);
                }
                short8 af = *(short8*)af32;
                const short8* bp0 = (const short8*)
                    (rb + col0 * 64 + (((koff >> 3) ^ (col0 & 7)) << 3));
                const short8* bp1 = (const short8*)
                    (rb + col1 * 64 + (((koff >> 3) ^ (col1 & 7)) << 3));
                acc0 = __builtin_amdgcn_mfma_f32_16x16x32_bf16(af, *bp0, acc0, 0, 0, 0);
                acc1 = __builtin_amdgcn_mfma_f32_16x16x32_bf16(af, *bp1, acc1, 0, 0, 0);
            }
            if (q < 7) {
                __syncthreads();        // all reads of rt[(q+1)&1] done
                *(short8*)(rt[(q + 1) & 1] + swz16(scol, skk)) = nxt;
                __syncthreads();
            }
        }
        __syncthreads();
        #pragma unroll
        for (int r = 0; r < 4; ++r) {
            int row = mb * 16 + (lane >> 4) * 4 + r;
            float iv = invd[row];
            Fb[swz16(row, col0)] = (u16)f2bf(acc0[r] * iv);
            Fb[swz16(row, col1)] = (u16)f2bf(acc1[r] * iv);
        }
        __syncthreads();

        // ---- MFMA2: H1 = relu(F @ w1e^T + b1) -> H1b (overlays Hn) ----
        f32x4 ac20 = {0.f, 0.f, 0.f, 0.f}, ac21 = {0.f, 0.f, 0.f, 0.f};
        #pragma unroll
        for (int ks = 0; ks < 2; ++ks) {
            int kb = ks * 32 + kgrp;
            const short8* ap = (const short8*)
                (Fb + arow * 64 + (((kb >> 3) ^ (arow & 7)) << 3));
            const short8* bp0 = (const short8*)
                (w1s + col0 * 64 + (((kb >> 3) ^ (col0 & 7)) << 3));
            const short8* bp1 = (const short8*)
                (w1s + col1 * 64 + (((kb >> 3) ^ (col1 & 7)) << 3));
            ac20 = __builtin_amdgcn_mfma_f32_16x16x32_bf16(*ap, *bp0, ac20, 0, 0, 0);
            ac21 = __builtin_amdgcn_mfma_f32_16x16x32_bf16(*ap, *bp1, ac21, 0, 0, 0);
        }
        __syncthreads();
        #pragma unroll
        for (int r = 0; r < 4; ++r) {
            int row = mb * 16 + (lane >> 4) * 4 + r;
            H1b[swz16(row, col0)] = (u16)f2bf(fmaxf(ac20[r] + b1s[col0], 0.f));
            H1b[swz16(row, col1)] = (u16)f2bf(fmaxf(ac21[r] + b1s[col1], 0.f));
        }
        __syncthreads();

        // ---- MFMA3: O = H1 @ w2^T + b2; blend & store ----
        f32x4 ac30 = {0.f, 0.f, 0.f, 0.f}, ac31 = {0.f, 0.f, 0.f, 0.f};
        #pragma unroll
        for (int ks = 0; ks < 2; ++ks) {
            int kb = ks * 32 + kgrp;
            const short8* ap = (const short8*)
                (H1b + arow * 64 + (((kb >> 3) ^ (arow & 7)) << 3));
            const short8* bp0 = (const short8*)
                (w2s + col0 * 64 + (((kb >> 3) ^ (col0 & 7)) << 3));
            const short8* bp1 = (const short8*)
                (w2s + col1 * 64 + (((kb >> 3) ^ (col1 & 7)) << 3));
            ac30 = __builtin_amdgcn_mfma_f32_16x16x32_bf16(*ap, *bp0, ac30, 0, 0, 0);
            ac31 = __builtin_amdgcn_mfma_f32_16x16x32_bf16(*ap, *bp1, ac31, 0, 0, 0);
        }
        #pragma unroll
        for (int r = 0; r < 4; ++r) {
            int row = mb * 16 + (lane >> 4) * 4 + r;
            int n = (w << WSH) + row;
            if (n >= N) continue;
            int c = cnts[row];
            if (c > 0 && selfc[row] == c) continue;  // all-self: branch a
            #pragma unroll
            for (int q = 0; q < 2; ++q) {
                int col = (nb0 + q) * 16 + (lane & 15);
                float o = (q == 0 ? ac30[r] : ac31[r]) + b2s[col];
                float f = bf2f(Fb[swz16(row, col)]);
                out[n * DD + col] = (c == 0) ? ctx_s[col] : (1.f - sc) * f + sc * o;
            }
        }
        // rare all-self nodes: branch-a MLP inline (wave 0; ~never executes)
        if (wv == 0) {
            bool fl;
            {
                int c = cnts[lane];
                fl = (c > 0) && (selfc[lane] == c) && ((w << WSH) + lane < N);
            }
            unsigned long long m = __ballot(fl);
            float cx = ctx_s[lane];
            while (m) {
                int rr = __ffsll(m) - 1;
                m &= m - 1;
                int n = (w << WSH) + rr;
                float f = bf2f(Fb[swz16(rr, lane)]);
                float h = b1a[lane];
                for (int k = 0; k < DD; ++k)
                    h = fmaf(__shfl(f, k), w1a[lane * 2 * DD + k], h);
                for (int k = 0; k < DD; ++k)
                    h = fmaf(__shfl(cx, k), w1a[lane * 2 * DD + DD + k], h);
                h = fmaxf(h, 0.f);
                float o = b2a[lane];
                for (int k = 0; k < DD; ++k)
                    o = fmaf(__shfl(h, k), w2a[lane * DD + k], o);
                out[n * DD + lane] = (1.f - sc) * f + sc * o;
            }
        }
    }
}

// ---------------------------------------------------------------------------
extern "C" void kernel_launch(void* const* d_in, const int* in_sizes, int n_in,
                              void* d_out, int out_size, void* d_ws, size_t ws_size,
                              hipStream_t stream) {
    const int*   edge_index = (const int*)d_in[0];     // [2, E]
    const int*   etype      = (const int*)d_in[1];     // [E]
    const float* rel        = (const float*)d_in[2];   // [R, 64]
    const float* w1a        = (const float*)d_in[3];
    const float* b1a        = (const float*)d_in[4];
    const float* w2a        = (const float*)d_in[5];
    const float* b2a        = (const float*)d_in[6];
    const float* w1b        = (const float*)d_in[7];
    const float* b1b        = (const float*)d_in[8];
    const float* w2b        = (const float*)d_in[9];
    const float* b2b        = (const float*)d_in[10];
    const float* strength   = (const float*)d_in[11];

    int E = in_sizes[0] / 2;
    int R = in_sizes[2] / DD;   // == RK
    int N = out_size / DD;
    int GW = (N + WSZ - 1) >> WSH;      // 64-node windows

    float* out = (float*)d_out;
    char*  p   = (char*)d_ws;

    int*   gcur    = (int*)p;   p += (size_t)GW * sizeof(int);
    int*   slcnt   = (int*)p;   p += sizeof(int);       // == gcur + GW
    float* ctxpart = (float*)p; p += 8 * DD * sizeof(float);
    p = (char*)(((size_t)p + 15) & ~(size_t)15);
    u16*   relT     = (u16*)p; p += (size_t)RK * DD * sizeof(u16);
    u16*   w1t      = (u16*)p; p += (size_t)DD * DD * sizeof(u16);
    u16*   w2t      = (u16*)p; p += (size_t)DD * DD * sizeof(u16);
    u32*   selflist = (u32*)p; p += (size_t)SMAX * sizeof(u32);
    u16*   es       = (u16*)p;  // GW*CAP u16 = 12.8 MB (16B-aligned)

    k_prep<<<9, 512, 0, stream>>>(rel, R, ctxpart, relT, w1b, w2b, w1t, w2t,
                                  gcur, GW);

    const int* src = edge_index;
    const int* dst = edge_index + E;
    int nb = (E + TILE - 1) / TILE;

    k_gplace<<<nb, 512, 0, stream>>>(src, dst, etype, gcur, es,
                                     selflist, slcnt, E, GW);

    int nwb = (GW + 1) / 2;             // persistent: 2 windows per block
    k_win<<<nwb, 512, 0, stream>>>(es, gcur, relT, w1t, w2t, ctxpart, R,
                                   b1b, b2b, strength, out,
                                   selflist, slcnt, w1a, b1a, w2a, b2a, N, GW);
}